// Round 14
// baseline (878.772 us; speedup 1.0000x reference)
//
#include <hip/hip_runtime.h>

#define B_DIM 4
#define T_DIM 16
#define HW_DIM 4096
#define C_DIM 64
#define GN_EPS 1e-5f
#define NSUC (B_DIM * (T_DIM - 1) * HW_DIM)  // 245760 successor slots

__device__ __forceinline__ float leaky(float x) { return x > 0.f ? x : 0.01f * x; }

// ---------------- pass 1: count edges per successor node ----------------
__global__ __launch_bounds__(256, 8) void count_kernel(
    const int* __restrict__ edge, int* __restrict__ cnt, int E)
{
    int e = blockIdx.x * blockDim.x + threadIdx.x;
    if (e >= E) return;
    const int4 ev = ((const int4*)edge)[e];
    const int sc = (ev.x * (T_DIM - 1) + ev.y) * HW_DIM + ev.w;
    atomicAdd(&cnt[sc], 1);
}

// ---------------- pass 2: exclusive offsets (wave scan + 1 atomic/wave) ----------------
__global__ __launch_bounds__(256, 8) void offset_kernel(
    const int* __restrict__ cnt, int* __restrict__ off, int* __restrict__ cursor, int n)
{
    int i = blockIdx.x * blockDim.x + threadIdx.x;
    int c = (i < n) ? cnt[i] : 0;
    const int lane = threadIdx.x & 63;
    int pre = c;
#pragma unroll
    for (int d = 1; d < 64; d <<= 1) {
        int t = __shfl_up(pre, d);
        if (lane >= d) pre += t;
    }
    int tot = __shfl(pre, 63);
    int base = 0;
    if (lane == 63) base = atomicAdd(cursor, tot);
    base = __shfl(base, 63);
    if (i < n) off[i] = base + pre - c;
}

// ---------------- pass 3: per-edge GN stats + payload fill (edge-per-lane) ----------------
// payload: pay4 {pd0, pd1, w*rs, w}, pay2 {w*rs*mean, fp_bits}
__global__ __launch_bounds__(256, 4) void stats_fill_kernel(
    const int* __restrict__ edge, const float* __restrict__ pos,
    const float* __restrict__ weight,
    const float* __restrict__ W1, const float* __restrict__ b1,
    const float* __restrict__ W2, const float* __restrict__ b2,
    const int* __restrict__ off, int* __restrict__ fill,
    float4* __restrict__ pay4, float2* __restrict__ pay2, int E)
{
    int e = blockIdx.x * blockDim.x + threadIdx.x;
    if (e >= E) return;
    const int4 ev = ((const int4*)edge)[e];
    const int sc = (ev.x * (T_DIM - 1) + ev.y) * HW_DIM + ev.w;

    const float2 pp = ((const float2*)pos)[ev.y * HW_DIM + ev.z];
    const float2 ps = ((const float2*)pos)[(ev.y + 1) * HW_DIM + ev.w];
    const float pd0 = ps.x - pp.x;
    const float pd1 = ps.y - pp.y;

    float d[C_DIM];
#pragma unroll
    for (int c = 0; c < C_DIM; c++) d[c] = b2[c];
#pragma unroll
    for (int kk = 0; kk < C_DIM; kk++) {
        const float hv = leaky(fmaf(pd0, W1[kk], fmaf(pd1, W1[C_DIM + kk], b1[kk])));
#pragma unroll
        for (int c = 0; c < C_DIM; c++) d[c] = fmaf(hv, W2[kk * C_DIM + c], d[c]);
    }
    float s = 0.f, sq = 0.f;
#pragma unroll
    for (int c = 0; c < C_DIM; c++) { s += d[c]; sq = fmaf(d[c], d[c], sq); }
    const float mean = s * (1.f / C_DIM);
    const float var = sq * (1.f / C_DIM) - mean * mean;
    const float rsv = rsqrtf(var + GN_EPS);

    const float w = weight[e];
    const float wrs = w * rsv;
    const int fp = (ev.x * T_DIM + ev.y) * HW_DIM + ev.z;

    const int slot = atomicAdd(&fill[sc], 1);
    const int idx = off[sc] + slot;
    pay4[idx] = make_float4(pd0, pd1, wrs, w);
    pay2[idx] = make_float2(wrs * mean, __int_as_float(fp));
}

// ---------------- pass 4: node kernel, 16 lanes per node (4 channels/lane) ----------------
// GEMV broadcast via group-private LDS slot: 1 ds_write_b128 + 16 ds_read_b128
// (group-uniform addr -> HW broadcast; 17-float4 stride => 4 groups/wave hit
// distinct banks). Wave-lockstep makes write/read/rewrite safe w/o barriers.
__global__ __launch_bounds__(256, 4) void node16_kernel(
    const float* __restrict__ gf,
    const float* __restrict__ W1, const float* __restrict__ b1,
    const float* __restrict__ W2, const float* __restrict__ b2,
    const float* __restrict__ gdg, const float* __restrict__ gdb,
    const float* __restrict__ Wa, const float* __restrict__ ba,
    const float* __restrict__ gng, const float* __restrict__ gnb,
    const float* __restrict__ Wf, const float* __restrict__ bf,
    const float* __restrict__ gfg, const float* __restrict__ gfb,
    const int* __restrict__ cnt, const int* __restrict__ off,
    const float4* __restrict__ pay4, const float2* __restrict__ pay2,
    float* __restrict__ out, int N)
{
    __shared__ float4 lds_src[16 * 17];   // 16 groups x 17 float4 (stride-pad)

    const int tid = blockIdx.x * blockDim.x + threadIdx.x;
    const int n = tid >> 4;
    if (n >= N) return;
    const int lig = tid & 15;             // lane-in-group, owns channels [4*lig, 4*lig+4)
    const int grp = threadIdx.x >> 4;     // group within block (0..15)
    const int ldsBase = grp * 17;
    const int cb = 4 * lig;

    const float4 g = *(const float4*)(gf + (long)n * C_DIM + cb);
    float* orow = out + (long)n * C_DIM + cb;

    const int t = (n >> 12) & (T_DIM - 1);
    int k = 0, sc = 0;
    if (t > 0) {
        const int b = n >> 16;
        sc = n - (b + 1) * HW_DIM;
        k = cnt[sc];
    }
    if (k == 0) { *(float4*)orow = g; return; }

    const int base = off[sc];
    const float4 w1a = *(const float4*)(W1 + cb);
    const float4 w1b = *(const float4*)(W1 + C_DIM + cb);
    const float4 b1v = *(const float4*)(b1 + cb);

    float4 hacc = make_float4(0.f, 0.f, 0.f, 0.f);
    float4 vacc = make_float4(0.f, 0.f, 0.f, 0.f);
    float sw = 0.f, srs = 0.f, srm = 0.f;

    for (int j = 0; j < k; j++) {
        const float4 p = pay4[base + j];          // {pd0, pd1, wrs, w} uniform in group
        const float2 q = pay2[base + j];          // {wrsm, fp}
        const int fp = __float_as_int(q.y);

        float4 hv;
        hv.x = leaky(fmaf(p.x, w1a.x, fmaf(p.y, w1b.x, b1v.x)));
        hv.y = leaky(fmaf(p.x, w1a.y, fmaf(p.y, w1b.y, b1v.y)));
        hv.z = leaky(fmaf(p.x, w1a.z, fmaf(p.y, w1b.z, b1v.z)));
        hv.w = leaky(fmaf(p.x, w1a.w, fmaf(p.y, w1b.w, b1v.w)));
        hacc.x = fmaf(p.z, hv.x, hacc.x);
        hacc.y = fmaf(p.z, hv.y, hacc.y);
        hacc.z = fmaf(p.z, hv.z, hacc.z);
        hacc.w = fmaf(p.z, hv.w, hacc.w);

        const float4 v = *(const float4*)(gf + (long)fp * C_DIM + cb);  // coalesced 256B/group
        vacc.x = fmaf(p.w, v.x, vacc.x);
        vacc.y = fmaf(p.w, v.y, vacc.y);
        vacc.z = fmaf(p.w, v.z, vacc.z);
        vacc.w = fmaf(p.w, v.w, vacc.w);

        sw += p.w; srs += p.z; srm += q.x;
    }

    // GEMV: stage src in LDS, broadcast-read 4 source values at a time.
#define GEMV_PASS(src4, Wbase, acc)                                            \
    lds_src[ldsBase + lig] = (src4);                                           \
    _Pragma("unroll")                                                          \
    for (int k4 = 0; k4 < 16; k4++) {                                          \
        const float4 sv = lds_src[ldsBase + k4];                               \
        const float4 wv0 = *(const float4*)((Wbase) + (4 * k4 + 0) * C_DIM + cb); \
        const float4 wv1 = *(const float4*)((Wbase) + (4 * k4 + 1) * C_DIM + cb); \
        const float4 wv2 = *(const float4*)((Wbase) + (4 * k4 + 2) * C_DIM + cb); \
        const float4 wv3 = *(const float4*)((Wbase) + (4 * k4 + 3) * C_DIM + cb); \
        acc.x = fmaf(sv.x, wv0.x, acc.x); acc.y = fmaf(sv.x, wv0.y, acc.y);    \
        acc.z = fmaf(sv.x, wv0.z, acc.z); acc.w = fmaf(sv.x, wv0.w, acc.w);    \
        acc.x = fmaf(sv.y, wv1.x, acc.x); acc.y = fmaf(sv.y, wv1.y, acc.y);    \
        acc.z = fmaf(sv.y, wv1.z, acc.z); acc.w = fmaf(sv.y, wv1.w, acc.w);    \
        acc.x = fmaf(sv.z, wv2.x, acc.x); acc.y = fmaf(sv.z, wv2.y, acc.y);    \
        acc.z = fmaf(sv.z, wv2.z, acc.z); acc.w = fmaf(sv.z, wv2.w, acc.w);    \
        acc.x = fmaf(sv.w, wv3.x, acc.x); acc.y = fmaf(sv.w, wv3.y, acc.y);    \
        acc.z = fmaf(sv.w, wv3.z, acc.z); acc.w = fmaf(sv.w, wv3.w, acc.w);    \
    }

    // t1 = hacc_full @ W2
    float4 t1 = make_float4(0.f, 0.f, 0.f, 0.f);
    GEMV_PASS(hacc, W2, t1)

    // uaccS = vacc + gdg*(t1 + srs*b2 - srm) + sw*gdb
    const float4 b2v = *(const float4*)(b2 + cb);
    const float4 gdgv = *(const float4*)(gdg + cb);
    const float4 gdbv = *(const float4*)(gdb + cb);
    float4 u;
    u.x = fmaf(gdgv.x, fmaf(srs, b2v.x, t1.x - srm), fmaf(sw, gdbv.x, vacc.x));
    u.y = fmaf(gdgv.y, fmaf(srs, b2v.y, t1.y - srm), fmaf(sw, gdbv.y, vacc.y));
    u.z = fmaf(gdgv.z, fmaf(srs, b2v.z, t1.z - srm), fmaf(sw, gdbv.z, vacc.z));
    u.w = fmaf(gdgv.w, fmaf(srs, b2v.w, t1.w - srm), fmaf(sw, gdbv.w, vacc.w));

    // c2 = u_full @ Wa + sw*ba
    const float4 bav = *(const float4*)(ba + cb);
    float4 c2 = make_float4(sw * bav.x, sw * bav.y, sw * bav.z, sw * bav.w);
    GEMV_PASS(u, Wa, c2)

    // GN(c2) over the 16-lane group
    float s = c2.x + c2.y + c2.z + c2.w;
    float sq = fmaf(c2.x, c2.x, fmaf(c2.y, c2.y, fmaf(c2.z, c2.z, c2.w * c2.w)));
#pragma unroll
    for (int m = 1; m < 16; m <<= 1) {
        s += __shfl_xor(s, m, 16);
        sq += __shfl_xor(sq, m, 16);
    }
    float mean = s * (1.f / C_DIM);
    float var = sq * (1.f / C_DIM) - mean * mean;
    float rs = rsqrtf(var + GN_EPS);
    const float4 gngv = *(const float4*)(gng + cb);
    const float4 gnbv = *(const float4*)(gnb + cb);
    float4 c2n;
    c2n.x = fmaf((c2.x - mean) * rs, gngv.x, gnbv.x);
    c2n.y = fmaf((c2.y - mean) * rs, gngv.y, gnbv.y);
    c2n.z = fmaf((c2.z - mean) * rs, gngv.z, gnbv.z);
    c2n.w = fmaf((c2.w - mean) * rs, gngv.w, gnbv.w);

    // d2 = bf + g_full @ Wf[0:64] + c2n_full @ Wf[64:128]
    const float4 bfv = *(const float4*)(bf + cb);
    float4 d2 = bfv;
    GEMV_PASS(g, Wf, d2)
    GEMV_PASS(c2n, Wf + C_DIM * C_DIM, d2)

    // final GN + leaky
    s = d2.x + d2.y + d2.z + d2.w;
    sq = fmaf(d2.x, d2.x, fmaf(d2.y, d2.y, fmaf(d2.z, d2.z, d2.w * d2.w)));
#pragma unroll
    for (int m = 1; m < 16; m <<= 1) {
        s += __shfl_xor(s, m, 16);
        sq += __shfl_xor(sq, m, 16);
    }
    mean = s * (1.f / C_DIM);
    var = sq * (1.f / C_DIM) - mean * mean;
    rs = rsqrtf(var + GN_EPS);
    const float4 gfgv = *(const float4*)(gfg + cb);
    const float4 gfbv = *(const float4*)(gfb + cb);
    float4 o;
    o.x = leaky(fmaf((d2.x - mean) * rs, gfgv.x, gfbv.x));
    o.y = leaky(fmaf((d2.y - mean) * rs, gfgv.y, gfbv.y));
    o.z = leaky(fmaf((d2.z - mean) * rs, gfgv.z, gfbv.z));
    o.w = leaky(fmaf((d2.w - mean) * rs, gfgv.w, gfbv.w));
    *(float4*)orow = o;
#undef GEMV_PASS
}

extern "C" void kernel_launch(void* const* d_in, const int* in_sizes, int n_in,
                              void* d_out, int out_size, void* d_ws, size_t ws_size,
                              hipStream_t stream) {
    const float* gf     = (const float*)d_in[0];
    const float* pos    = (const float*)d_in[1];
    const int*   edge   = (const int*)d_in[2];
    const float* weight = (const float*)d_in[3];
    const float* W1  = (const float*)d_in[4];
    const float* b1  = (const float*)d_in[5];
    const float* W2  = (const float*)d_in[6];
    const float* b2  = (const float*)d_in[7];
    const float* gdg = (const float*)d_in[8];
    const float* gdb = (const float*)d_in[9];
    const float* Wa  = (const float*)d_in[10];
    const float* ba  = (const float*)d_in[11];
    const float* gng = (const float*)d_in[12];
    const float* gnb = (const float*)d_in[13];
    const float* Wf  = (const float*)d_in[14];
    const float* bf  = (const float*)d_in[15];
    const float* gfg = (const float*)d_in[16];
    const float* gfb = (const float*)d_in[17];

    float* out = (float*)d_out;
    const int E = in_sizes[3];
    const int N = in_sizes[0] / C_DIM;

    // ws layout: [cursor 16B][cnt NSUC][fill NSUC][off NSUC][pay4 E*16][pay2 E*8]
    char* p = (char*)d_ws;
    int* cursor = (int*)p;
    int* cnt  = (int*)(p + 16);
    int* fill = (int*)(p + 16 + (size_t)NSUC * 4);
    int* off  = (int*)(p + 16 + (size_t)NSUC * 8);
    float4* pay4 = (float4*)(p + 16 + (size_t)NSUC * 12);
    float2* pay2 = (float2*)((char*)pay4 + (size_t)E * 16);

    // zero cursor + cnt + fill in one shot
    hipMemsetAsync(d_ws, 0, 16 + (size_t)NSUC * 8, stream);

    dim3 blk(256);
    count_kernel<<<dim3((E + 255) / 256), blk, 0, stream>>>(edge, cnt, E);
    offset_kernel<<<dim3((NSUC + 255) / 256), blk, 0, stream>>>(cnt, off, cursor, NSUC);
    stats_fill_kernel<<<dim3((E + 255) / 256), blk, 0, stream>>>(
        edge, pos, weight, W1, b1, W2, b2, off, fill, pay4, pay2, E);
    node16_kernel<<<dim3(((size_t)N * 16 + 255) / 256), blk, 0, stream>>>(
        gf, W1, b1, W2, b2, gdg, gdb, Wa, ba, gng, gnb, Wf, bf, gfg, gfb,
        cnt, off, pay4, pay2, out, N);
}